// Round 1
// baseline (376.420 us; speedup 1.0000x reference)
//
#include <hip/hip_runtime.h>
#include <stdint.h>

// Problem constants: B=2, S=2048, D=2048, H=16, HD=128 (multi-query: 1 KV head)
#define BATCH 2
#define SEQ   2048
#define DMOD  2048
#define NHEAD 16
#define HDIM  128

typedef __bf16 bf16x8 __attribute__((ext_vector_type(8)));
typedef float f32x4   __attribute__((ext_vector_type(4)));
typedef unsigned short u16x8 __attribute__((ext_vector_type(8)));

#define MFMA(a, b, c) __builtin_amdgcn_mfma_f32_16x16x32_bf16(a, b, c, 0, 0, 0)

__device__ __forceinline__ uint16_t f2bf(float f) {
  union { float f; uint32_t u; } cv; cv.f = f;
  uint32_t u = cv.u;
  return (uint16_t)((u + 0x7FFFu + ((u >> 16) & 1u)) >> 16);  // RNE
}

__device__ __forceinline__ void gload_lds16(const void* g, void* l) {
  // 16B per lane, LDS dest = wave-uniform base + lane*16 (linear)
  __builtin_amdgcn_global_load_lds(
      (__attribute__((address_space(1))) void*)g,
      (__attribute__((address_space(3))) void*)l, 16, 0, 0);
}

// ---------------- fp32 -> bf16 conversion (vectorized) ----------------
__global__ __launch_bounds__(256) void cvtbf16(const float* __restrict__ in,
                                               uint16_t* __restrict__ out, int n) {
  int i = (blockIdx.x * 256 + threadIdx.x) * 8;
  if (i >= n) return;
  f32x4 a = *(const f32x4*)&in[i];
  f32x4 b = *(const f32x4*)&in[i + 4];
  u16x8 o;
  o[0] = f2bf(a[0]); o[1] = f2bf(a[1]); o[2] = f2bf(a[2]); o[3] = f2bf(a[3]);
  o[4] = f2bf(b[0]); o[5] = f2bf(b[1]); o[6] = f2bf(b[2]); o[7] = f2bf(b[3]);
  *(u16x8*)&out[i] = o;
}

// ---------------- 128x128 GEMM tile body (m97 structure) ----------------
// C[m,n] = sum_k A[m,k]*W[n,k] + bias[n]; A: (M,lda) bf16, W: (N,K) bf16 rows.
template <bool OUT_F32>
__device__ __forceinline__ void gemm128_body(
    const uint16_t* __restrict__ A, int lda,
    const uint16_t* __restrict__ Bw,          // weight rows, stride K
    const float* __restrict__ bias,
    void* __restrict__ out, int ldc,
    int m0, int n0, int K,
    uint16_t* As, uint16_t* Bs) {
  const int t = threadIdx.x;
  const int lane = t & 63;
  const int w = t >> 6;
  const int half = lane >> 4;   // 0..3
  const int fr = lane & 15;     // 0..15
  const int wr = w >> 1, wc = w & 1;

  f32x4 acc[4][4] = {};

  // staging: A/B tiles 128x32 bf16 = 8KB each; 8 chunks of 1024B (64 lanes x 16B)
  const int r0 = (0 * 4 + w) * 16 + (lane >> 2);
  const int r1 = (1 * 4 + w) * 16 + (lane >> 2);
  const int sc0 = (lane & 3) * 8;

  const int nkt = K >> 5;
  for (int kt = 0; kt < nkt; ++kt) {
    const int kb = kt * 32;
    gload_lds16(&A[(size_t)(m0 + r0) * lda + kb + sc0], &As[(0 * 4 + w) * 512]);
    gload_lds16(&A[(size_t)(m0 + r1) * lda + kb + sc0], &As[(1 * 4 + w) * 512]);
    gload_lds16(&Bw[(size_t)(n0 + r0) * K + kb + sc0], &Bs[(0 * 4 + w) * 512]);
    gload_lds16(&Bw[(size_t)(n0 + r1) * K + kb + sc0], &Bs[(1 * 4 + w) * 512]);
    __syncthreads();
    bf16x8 af[4], bf[4];
#pragma unroll
    for (int i = 0; i < 4; ++i) {
      af[i] = *(const bf16x8*)&As[(wr * 64 + i * 16 + fr) * 32 + half * 8];
      bf[i] = *(const bf16x8*)&Bs[(wc * 64 + i * 16 + fr) * 32 + half * 8];
    }
#pragma unroll
    for (int i = 0; i < 4; ++i)
#pragma unroll
      for (int j = 0; j < 4; ++j)
        acc[i][j] = MFMA(af[i], bf[j], acc[i][j]);
    __syncthreads();
  }

  // epilogue: C/D layout col = lane&15, row = (lane>>4)*4 + reg
#pragma unroll
  for (int j = 0; j < 4; ++j) {
    const int col = wc * 64 + j * 16 + fr;
    const float bv = bias[n0 + col];
#pragma unroll
    for (int i = 0; i < 4; ++i) {
      const int rowb = m0 + wr * 64 + i * 16 + half * 4;
#pragma unroll
      for (int r = 0; r < 4; ++r) {
        const float v = acc[i][j][r] + bv;
        if (OUT_F32)
          ((float*)out)[(size_t)(rowb + r) * ldc + n0 + col] = v;
        else
          ((uint16_t*)out)[(size_t)(rowb + r) * ldc + n0 + col] = f2bf(v);
      }
    }
  }
}

// Fused Q/K/V projection. grid = (M/128, 18): y<16 -> Q tile, y==16 -> K, y==17 -> V
__global__ __launch_bounds__(256, 2) void qkv_gemm(
    const uint16_t* __restrict__ xb,
    const uint16_t* __restrict__ wqb, const float* __restrict__ bq,
    const uint16_t* __restrict__ wkb, const float* __restrict__ bk,
    const uint16_t* __restrict__ wvb, const float* __restrict__ bv,
    uint16_t* __restrict__ qb, uint16_t* __restrict__ kb, uint16_t* __restrict__ vb) {
  __shared__ uint16_t As[128 * 32];
  __shared__ uint16_t Bs[128 * 32];
  const int m0 = blockIdx.x * 128;
  const int y = blockIdx.y;
  const uint16_t* Bw;
  const float* bias;
  uint16_t* out;
  int n0, ldc;
  if (y < 16)       { Bw = wqb; bias = bq; out = qb; n0 = y * 128; ldc = DMOD; }
  else if (y == 16) { Bw = wkb; bias = bk; out = kb; n0 = 0;       ldc = HDIM; }
  else              { Bw = wvb; bias = bv; out = vb; n0 = 0;       ldc = HDIM; }
  gemm128_body<false>(xb, DMOD, Bw, bias, out, ldc, m0, n0, DMOD, As, Bs);
}

// Final output projection -> fp32
__global__ __launch_bounds__(256, 2) void o_gemm(
    const uint16_t* __restrict__ ab, const uint16_t* __restrict__ wob,
    const float* __restrict__ bo, float* __restrict__ out) {
  __shared__ uint16_t As[128 * 32];
  __shared__ uint16_t Bs[128 * 32];
  gemm128_body<true>(ab, DMOD, wob, bo, out, DMOD,
                     blockIdx.x * 128, blockIdx.y * 128, DMOD, As, Bs);
}

// ---------------- V transpose: (B*S, HD) -> (B, HD, S) ----------------
__global__ __launch_bounds__(256) void transpose_v(const uint16_t* __restrict__ vb,
                                                   uint16_t* __restrict__ vt) {
  __shared__ uint16_t tile[64][65];
  const int s0 = blockIdx.x * 64, d0 = blockIdx.y * 64, b = blockIdx.z;
  const int tx = threadIdx.x & 63, ty = threadIdx.x >> 6;
#pragma unroll
  for (int r = ty; r < 64; r += 4)
    tile[r][tx] = vb[((size_t)b * SEQ + s0 + r) * HDIM + d0 + tx];
  __syncthreads();
#pragma unroll
  for (int r = ty; r < 64; r += 4)
    vt[((size_t)b * HDIM + d0 + r) * SEQ + s0 + tx] = tile[tx][r];
}

// ---------------- flash MQA attention ----------------
// grid (S/128, H, B), 256 thr (4 waves). Wave w owns q-rows [qt*128+w*32, +32).
// K tile [64][128] and Vt tile [128][64] staged via global_load_lds with
// pre-swizzled SOURCE col (byte ^= (row&7)<<4) + swizzled READ (both-sides rule).
__global__ __launch_bounds__(256, 2) void mqa_attn(
    const uint16_t* __restrict__ qb,   // (B*S, D)
    const uint16_t* __restrict__ kb,   // (B*S, HD)
    const uint16_t* __restrict__ vt,   // (B, HD, S)
    uint16_t* __restrict__ ab) {       // (B*H*S, HD) contiguous
  __shared__ uint16_t Ks[64 * 128];    // swizzled
  __shared__ uint16_t Vs[128 * 64];    // swizzled, [d][k]
  __shared__ uint16_t Ps[4][32 * 72];  // per-wave P, row stride 72 (144B, 16B-aligned)

  const int t = threadIdx.x, lane = t & 63, w = t >> 6;
  const int half = lane >> 4, fr = lane & 15;
  const int qt = blockIdx.x, h = blockIdx.y, b = blockIdx.z;
  const size_t rowbase = (size_t)b * SEQ;
  const float scale = 0.08838834764831845f;  // 1/sqrt(128)

  // Q fragments in registers: rows q0 + i*16 + fr, k = c*32 + half*8
  const int q0 = qt * 128 + w * 32;
  bf16x8 qf[2][4];
#pragma unroll
  for (int i = 0; i < 2; ++i)
#pragma unroll
    for (int c = 0; c < 4; ++c)
      qf[i][c] = *(const bf16x8*)&qb[(rowbase + q0 + i * 16 + fr) * DMOD +
                                     h * HDIM + c * 32 + half * 8];

  f32x4 o[2][8] = {};
  float mrow[2][4], lrow[2][4];
#pragma unroll
  for (int i = 0; i < 2; ++i)
#pragma unroll
    for (int r = 0; r < 4; ++r) { mrow[i][r] = -1e30f; lrow[i][r] = 0.f; }

  for (int kt = 0; kt < SEQ / 64; ++kt) {
    __syncthreads();  // prior tile's compute done before restaging
#pragma unroll
    for (int c = 0; c < 4; ++c) {
      const int chunk = c * 4 + w;
      // K: row = key index; linear dest, swizzled source col
      const int krow = chunk * 4 + (lane >> 4);
      const int kcol = ((lane & 15) * 8) ^ ((krow & 7) << 3);
      gload_lds16(&kb[(rowbase + kt * 64 + krow) * HDIM + kcol], &Ks[chunk * 512]);
      // V: row = d index
      const int drow = chunk * 8 + (lane >> 3);
      const int dcol = ((lane & 7) * 8) ^ ((drow & 7) << 3);
      gload_lds16(&vt[((size_t)b * HDIM + drow) * SEQ + kt * 64 + dcol], &Vs[chunk * 512]);
    }
    __syncthreads();

    // scores: S[q, key] = Q . K
    f32x4 sc[2][4] = {};
#pragma unroll
    for (int j = 0; j < 4; ++j) {
      const int krow = j * 16 + fr;
#pragma unroll
      for (int c = 0; c < 4; ++c) {
        bf16x8 kf = *(const bf16x8*)&Ks[krow * 128 + ((c * 32 + half * 8) ^ ((krow & 7) << 3))];
        sc[0][j] = MFMA(qf[0][c], kf, sc[0][j]);
        sc[1][j] = MFMA(qf[1][c], kf, sc[1][j]);
      }
    }

    // online softmax per q-row (row owned by 16-lane group; reduce via shfl_xor)
#pragma unroll
    for (int i = 0; i < 2; ++i) {
#pragma unroll
      for (int r = 0; r < 4; ++r) {
        float mx = fmaxf(fmaxf(sc[i][0][r], sc[i][1][r]), fmaxf(sc[i][2][r], sc[i][3][r]));
        mx = fmaxf(mx, __shfl_xor(mx, 1));
        mx = fmaxf(mx, __shfl_xor(mx, 2));
        mx = fmaxf(mx, __shfl_xor(mx, 4));
        mx = fmaxf(mx, __shfl_xor(mx, 8));
        mx *= scale;
        const float mnew = fmaxf(mrow[i][r], mx);
        const float alpha = __expf(mrow[i][r] - mnew);
        mrow[i][r] = mnew;
        float sum = 0.f;
#pragma unroll
        for (int j = 0; j < 4; ++j) {
          const float p = __expf(sc[i][j][r] * scale - mnew);
          sum += p;
          Ps[w][(i * 16 + half * 4 + r) * 72 + j * 16 + fr] = f2bf(p);
        }
        sum += __shfl_xor(sum, 1);
        sum += __shfl_xor(sum, 2);
        sum += __shfl_xor(sum, 4);
        sum += __shfl_xor(sum, 8);
        lrow[i][r] = lrow[i][r] * alpha + sum;
#pragma unroll
        for (int db = 0; db < 8; ++db) o[i][db][r] *= alpha;
      }
    }

    // PV: O[q, d] += P[q, key] * V[key, d]  (Vs holds V^T[d][key], swizzled)
#pragma unroll
    for (int c2 = 0; c2 < 2; ++c2) {
      bf16x8 pf0 = *(const bf16x8*)&Ps[w][(0 * 16 + fr) * 72 + c2 * 32 + half * 8];
      bf16x8 pf1 = *(const bf16x8*)&Ps[w][(1 * 16 + fr) * 72 + c2 * 32 + half * 8];
#pragma unroll
      for (int db = 0; db < 8; ++db) {
        const int d = db * 16 + fr;
        bf16x8 vf = *(const bf16x8*)&Vs[d * 64 + ((c2 * 32 + half * 8) ^ ((d & 7) << 3))];
        o[0][db] = MFMA(pf0, vf, o[0][db]);
        o[1][db] = MFMA(pf1, vf, o[1][db]);
      }
    }
  }

  // epilogue: normalize, write (b,h,s,hd)-contiguous (== reference's scrambled reshape)
#pragma unroll
  for (int i = 0; i < 2; ++i)
#pragma unroll
    for (int r = 0; r < 4; ++r) {
      const float inv = 1.f / lrow[i][r];
      const int qrow = q0 + i * 16 + half * 4 + r;
      const size_t orow = (size_t)(b * NHEAD + h) * SEQ + qrow;
#pragma unroll
      for (int db = 0; db < 8; ++db)
        ab[orow * HDIM + db * 16 + fr] = f2bf(o[i][db][r] * inv);
    }
}

// ---------------- host launch ----------------
extern "C" void kernel_launch(void* const* d_in, const int* in_sizes, int n_in,
                              void* d_out, int out_size, void* d_ws, size_t ws_size,
                              hipStream_t stream) {
  const float* x    = (const float*)d_in[0];
  const float* Wq_w = (const float*)d_in[1];
  const float* Wq_b = (const float*)d_in[2];
  const float* Wk_w = (const float*)d_in[3];
  const float* Wk_b = (const float*)d_in[4];
  const float* Wv_w = (const float*)d_in[5];
  const float* Wv_b = (const float*)d_in[6];
  const float* Wo_w = (const float*)d_in[7];
  const float* Wo_b = (const float*)d_in[8];
  float* out = (float*)d_out;

  char* ws = (char*)d_ws;
  // layout (bytes); xb aliased by ab (xb dead after qkv), wqb aliased by vt
  uint16_t* xb  = (uint16_t*)(ws + 0);         // 16 MB  (B*S, D) bf16
  uint16_t* ab  = xb;                          // 16 MB  (B*H*S, HD) bf16 attn out
  uint16_t* wqb = (uint16_t*)(ws + 16777216);  // 8 MB
  uint16_t* vt  = wqb;                         // 1 MB   (B, HD, S)
  uint16_t* wkb = (uint16_t*)(ws + 25165824);  // 0.5 MB
  uint16_t* wvb = (uint16_t*)(ws + 25690112);  // 0.5 MB
  uint16_t* wob = (uint16_t*)(ws + 26214400);  // 8 MB
  uint16_t* qb  = (uint16_t*)(ws + 34603008);  // 16 MB  (B*S, D)
  uint16_t* kb  = (uint16_t*)(ws + 51380224);  // 1 MB   (B*S, HD)
  uint16_t* vb  = (uint16_t*)(ws + 52428800);  // 1 MB   (B*S, HD)
  // total 53,477,376 bytes

  cvtbf16<<<4096, 256, 0, stream>>>(x, xb, BATCH * SEQ * DMOD);
  cvtbf16<<<2048, 256, 0, stream>>>(Wq_w, wqb, DMOD * DMOD);
  cvtbf16<<<128, 256, 0, stream>>>(Wk_w, wkb, HDIM * DMOD);
  cvtbf16<<<128, 256, 0, stream>>>(Wv_w, wvb, HDIM * DMOD);
  cvtbf16<<<2048, 256, 0, stream>>>(Wo_w, wob, DMOD * DMOD);

  qkv_gemm<<<dim3(32, 18), 256, 0, stream>>>(xb, wqb, Wq_b, wkb, Wk_b, wvb, Wv_b,
                                             qb, kb, vb);
  transpose_v<<<dim3(32, 2, 2), 256, 0, stream>>>(vb, vt);
  mqa_attn<<<dim3(16, 16, 2), 256, 0, stream>>>(qb, kb, vt, ab);
  o_gemm<<<dim3(32, 16), 256, 0, stream>>>(ab, wob, Wo_b, out);
}